// Round 5
// baseline (323.166 us; speedup 1.0000x reference)
//
#include <hip/hip_runtime.h>
#include <hip/hip_fp16.h>
#include <hip/hip_cooperative_groups.h>

namespace cg = cooperative_groups;

#define N_NODES 50000
#define N_EDGES 800000
#define F_IN   128
#define F_MID  64
#define F_OUT  40

// ---- cooperative counting-sort CSR build: 196 blocks (1/CU co-resident) ----
#define NSLICE 196                                  // node slices of 256 (slice = node >> 8)
#define CCHUNK ((N_EDGES + NSLICE - 1) / NSLICE)    // 4082 edges per chunk
#define NC2    (NSLICE * NSLICE)                    // counts matrix [slice][chunk]

// All atomics LDS-scope; all global writes contiguous (round-1 lesson).
// grid.sync() replaces 5 kernel boundaries (round-3/4 structure had 6 sort kernels).

__global__ __launch_bounds__(256, 1) void build_all(const int* __restrict__ ei,
                                                    int* __restrict__ counts,
                                                    int* __restrict__ bsum,
                                                    int* __restrict__ choff,
                                                    int* __restrict__ pairs,
                                                    int* __restrict__ rowptr,
                                                    float* __restrict__ dinv,
                                                    int* __restrict__ srcs) {
    cg::grid_group grid = cg::this_grid();
    __shared__ int sh[256];
    __shared__ int wpart[4];
    const int tid = threadIdx.x;
    const int bid = blockIdx.x;
    const int lane = tid & 63, wv = tid >> 6;

    // ---- P1: block = edge chunk; LDS histogram over dst slices ----
    if (tid < NSLICE) sh[tid] = 0;
    __syncthreads();
    int e0 = bid * CCHUNK;
    int e1 = e0 + CCHUNK; if (e1 > N_EDGES) e1 = N_EDGES;
    for (int e = e0 + tid; e < e1; e += 256)
        atomicAdd(&sh[ei[N_EDGES + e] >> 8], 1);
    __syncthreads();
    if (tid < NSLICE) counts[tid * NSLICE + bid] = sh[tid];   // [slice][chunk]
    grid.sync();

    // ---- P2a: block = slice; exclusive scan of its row, row total -> bsum ----
    int v = (tid < NSLICE) ? counts[bid * NSLICE + tid] : 0;
    int inc = v;
#pragma unroll
    for (int st = 1; st < 64; st <<= 1) {
        int t = __shfl_up(inc, st, 64);
        if (lane >= st) inc += t;
    }
    if (lane == 63) wpart[wv] = inc;
    __syncthreads();
    int woff = 0;
    for (int w = 0; w < wv; ++w) woff += wpart[w];
    int ex = woff + inc - v;                       // exclusive prefix within slice row
    if (tid == 0) bsum[bid] = wpart[0] + wpart[1] + wpart[2] + wpart[3];
    grid.sync();

    // ---- P2b: every block redundantly computes its slice offset (sum of bsum[0..bid)) ----
    int bv = (tid < bid) ? bsum[tid] : 0;
    int sv = bv;
#pragma unroll
    for (int off = 32; off > 0; off >>= 1) sv += __shfl_xor(sv, off, 64);
    if (lane == 0) wpart[wv] = sv;
    __syncthreads();
    int boffs = wpart[0] + wpart[1] + wpart[2] + wpart[3];
    if (tid < NSLICE) choff[bid * NSLICE + tid] = ex + boffs;
    grid.sync();

    // ---- P3: block = chunk; scatter packed edges via LDS cursors ----
    if (tid < NSLICE) sh[tid] = choff[tid * NSLICE + bid];
    __syncthreads();
    for (int e = e0 + tid; e < e1; e += 256) {
        int r = ei[e];
        int c = ei[N_EDGES + e];
        int pos = atomicAdd(&sh[c >> 8], 1);
        pairs[pos] = r | ((c & 255) << 16);        // src | dst-within-slice
    }
    grid.sync();

    // ---- P4: block = slice; per-slice CSR (rowptr, dinv, srcs) ----
    int base = choff[bid * NSLICE];
    int end  = (bid == NSLICE - 1) ? N_EDGES : choff[(bid + 1) * NSLICE];
    sh[tid] = 0;
    __syncthreads();
    for (int i = base + tid; i < end; i += 256)
        atomicAdd(&sh[pairs[i] >> 16], 1);
    __syncthreads();
    int v2 = sh[tid];
    int inc2 = v2;
#pragma unroll
    for (int st = 1; st < 64; st <<= 1) {
        int t = __shfl_up(inc2, st, 64);
        if (lane >= st) inc2 += t;
    }
    if (lane == 63) wpart[wv] = inc2;
    __syncthreads();
    int woff2 = 0;
    for (int w = 0; w < wv; ++w) woff2 += wpart[w];
    int ex2 = woff2 + inc2 - v2;                   // exclusive prefix within slice
    __syncthreads();
    sh[tid] = ex2;                                 // reuse as cursor (own slot only)
    int node = bid * 256 + tid;
    if (node < N_NODES) {
        rowptr[node] = base + ex2;
        dinv[node]   = rsqrtf((float)v2 + 1.0f);   // +1 = self loop
    }
    if (node == N_NODES - 1) rowptr[N_NODES] = N_EDGES;
    __syncthreads();
    for (int i = base + tid; i < end; i += 256) {
        int p = pairs[i];
        int pos = atomicAdd(&sh[p >> 16], 1);
        srcs[base + pos] = p & 0xFFFF;
    }
}

// ---------------- GEMM1: hw1h = fp16( (x @ W1) * dinv[row] )  (rows = 64 halves = 128 B) ----

__global__ __launch_bounds__(256) void gemm1_kernel(const float* __restrict__ x,
                                                    const float* __restrict__ W1,
                                                    const float* __restrict__ dinv,
                                                    __half* __restrict__ hw1h) {
    __shared__ float sW[F_IN * F_MID];   // 32 KB, row-major [k][c]
    __shared__ float sX[64][68];         // 17 KB, one K-half, padded
    int tid = threadIdx.x;
    const float4* W4 = (const float4*)W1;
    float4* sW4 = (float4*)sW;
    for (int i = tid; i < F_IN * F_MID / 4; i += 256) sW4[i] = W4[i];

    int row0 = blockIdx.x * 64;
    int tx = tid & 15, ty = tid >> 4;
    int c0 = tx * 4, r0 = ty * 4;
    float acc[4][4] = {};

    for (int p = 0; p < 2; ++p) {
        __syncthreads();
#pragma unroll
        for (int it = 0; it < 4; ++it) {
            int i = (tid + it * 256) * 4;
            int r = i >> 6, k = i & 63;
            float4 v = make_float4(0.f, 0.f, 0.f, 0.f);
            if (row0 + r < N_NODES)
                v = *(const float4*)&x[(size_t)(row0 + r) * F_IN + p * 64 + k];
            *(float4*)&sX[r][k] = v;
        }
        __syncthreads();
        const float* sWp = sW + p * 64 * F_MID;
#pragma unroll 4
        for (int k = 0; k < 64; ++k) {
            float4 w = *(const float4*)&sWp[k * F_MID + c0];
            float a0 = sX[r0 + 0][k];
            float a1 = sX[r0 + 1][k];
            float a2 = sX[r0 + 2][k];
            float a3 = sX[r0 + 3][k];
            acc[0][0] = fmaf(a0, w.x, acc[0][0]); acc[0][1] = fmaf(a0, w.y, acc[0][1]);
            acc[0][2] = fmaf(a0, w.z, acc[0][2]); acc[0][3] = fmaf(a0, w.w, acc[0][3]);
            acc[1][0] = fmaf(a1, w.x, acc[1][0]); acc[1][1] = fmaf(a1, w.y, acc[1][1]);
            acc[1][2] = fmaf(a1, w.z, acc[1][2]); acc[1][3] = fmaf(a1, w.w, acc[1][3]);
            acc[2][0] = fmaf(a2, w.x, acc[2][0]); acc[2][1] = fmaf(a2, w.y, acc[2][1]);
            acc[2][2] = fmaf(a2, w.z, acc[2][2]); acc[2][3] = fmaf(a2, w.w, acc[2][3]);
            acc[3][0] = fmaf(a3, w.x, acc[3][0]); acc[3][1] = fmaf(a3, w.y, acc[3][1]);
            acc[3][2] = fmaf(a3, w.z, acc[3][2]); acc[3][3] = fmaf(a3, w.w, acc[3][3]);
        }
    }
#pragma unroll
    for (int j = 0; j < 4; ++j) {
        int row = row0 + r0 + j;
        if (row < N_NODES) {
            float d = dinv[row];
            __half2 p0 = __floats2half2_rn(acc[j][0] * d, acc[j][1] * d);
            __half2 p1 = __floats2half2_rn(acc[j][2] * d, acc[j][3] * d);
            uint2 u = make_uint2(*reinterpret_cast<unsigned int*>(&p0),
                                 *reinterpret_cast<unsigned int*>(&p1));
            *reinterpret_cast<uint2*>(&hw1h[(size_t)row * F_MID + c0]) = u;
        }
    }
}

// ---------------- gather1: h = relu(dinv*(sum hw1h[src] + hw1h[n]) + b1)  (fp32 out) --------
// Wave = 4 edge groups x 16 quad lanes; each row = one aligned 128 B line (fp16 x 64).

__global__ __launch_bounds__(256) void gather1_kernel(const int* __restrict__ rowptr,
                                                      const int* __restrict__ srcs,
                                                      const __half* __restrict__ hw1h,
                                                      const float* __restrict__ dinv,
                                                      const float* __restrict__ b1,
                                                      float* __restrict__ h) {
    int n = blockIdx.x * 4 + (threadIdx.x >> 6);
    int lane = threadIdx.x & 63;
    int g = lane >> 4;          // edge slot 0..3
    int q = lane & 15;          // feature quad 0..15
    int s = __builtin_amdgcn_readfirstlane(rowptr[n]);
    int e = __builtin_amdgcn_readfirstlane(rowptr[n + 1]);
    const uint2* vb = (const uint2*)hw1h;          // row = 16 x uint2 (4 halves each)
    float4 acc = make_float4(0.f, 0.f, 0.f, 0.f);
#define UNPACK_ADD(u)                                                     \
    {   __half2 _h0 = *reinterpret_cast<__half2*>(&(u).x);                \
        __half2 _h1 = *reinterpret_cast<__half2*>(&(u).y);                \
        float2 _f0 = __half22float2(_h0);                                 \
        float2 _f1 = __half22float2(_h1);                                 \
        acc.x += _f0.x; acc.y += _f0.y; acc.z += _f1.x; acc.w += _f1.y; }
    int j = s + g;
    for (; j + 12 < e; j += 16) {                  // 16 edges/iter in flight per wave
        int i0 = srcs[j], i1 = srcs[j + 4], i2 = srcs[j + 8], i3 = srcs[j + 12];
        uint2 u0 = vb[(size_t)i0 * 16 + q];
        uint2 u1 = vb[(size_t)i1 * 16 + q];
        uint2 u2 = vb[(size_t)i2 * 16 + q];
        uint2 u3 = vb[(size_t)i3 * 16 + q];
        UNPACK_ADD(u0) UNPACK_ADD(u1) UNPACK_ADD(u2) UNPACK_ADD(u3)
    }
    for (; j + 4 < e; j += 8) {
        int i0 = srcs[j], i1 = srcs[j + 4];
        uint2 u0 = vb[(size_t)i0 * 16 + q];
        uint2 u1 = vb[(size_t)i1 * 16 + q];
        UNPACK_ADD(u0) UNPACK_ADD(u1)
    }
    if (j < e) {
        uint2 u0 = vb[(size_t)srcs[j] * 16 + q];
        UNPACK_ADD(u0)
    }
    // combine the 4 edge groups (per node, not per edge)
    acc.x += __shfl_xor(acc.x, 16, 64); acc.y += __shfl_xor(acc.y, 16, 64);
    acc.z += __shfl_xor(acc.z, 16, 64); acc.w += __shfl_xor(acc.w, 16, 64);
    acc.x += __shfl_xor(acc.x, 32, 64); acc.y += __shfl_xor(acc.y, 32, 64);
    acc.z += __shfl_xor(acc.z, 32, 64); acc.w += __shfl_xor(acc.w, 32, 64);
    float d = dinv[n];
    uint2 us = vb[(size_t)n * 16 + q];
    __half2 s0 = *reinterpret_cast<__half2*>(&us.x);
    __half2 s1 = *reinterpret_cast<__half2*>(&us.y);
    float2 f0 = __half22float2(s0), f1 = __half22float2(s1);
    float4 bq = *(const float4*)&b1[q * 4];
    float4 hv;
    hv.x = fmaxf(fmaf(d, acc.x + f0.x, bq.x), 0.f);
    hv.y = fmaxf(fmaf(d, acc.y + f0.y, bq.y), 0.f);
    hv.z = fmaxf(fmaf(d, acc.z + f1.x, bq.z), 0.f);
    hv.w = fmaxf(fmaf(d, acc.w + f1.y, bq.w), 0.f);
    if (g == 0) *(float4*)&h[(size_t)n * F_MID + q * 4] = hv;
}

// ---------------- GEMM2: hw2h = fp16( (h @ W2) * dinv[row] ), rows padded 40 -> 64 halves ----

__global__ __launch_bounds__(256) void gemm2_kernel(const float* __restrict__ h,
                                                    const float* __restrict__ W2,
                                                    const float* __restrict__ dinv,
                                                    __half* __restrict__ hw2h) {
    __shared__ float sW[F_MID * F_OUT];  // 10 KB
    for (int i = threadIdx.x; i < F_MID * F_OUT; i += 256) sW[i] = W2[i];
    __syncthreads();
    int idx = blockIdx.x * 256 + threadIdx.x;      // over N_NODES * 64 (padded)
    int r = idx >> 6;
    int c = idx & 63;
    float acc = 0.f;
    if (c < F_OUT) {
        const float* hr = h + (size_t)r * F_MID;
#pragma unroll
        for (int k = 0; k < F_MID; ++k) acc = fmaf(hr[k], sW[k * F_OUT + c], acc);
        acc *= dinv[r];
    }
    hw2h[idx] = __float2half(acc);                 // cols 40..63 = 0 (inert in gather)
}

// ---------------- gather2 + softmax (fp16 rows, one 128 B line per edge) ----------------

__global__ __launch_bounds__(256) void gather2_softmax_kernel(const int* __restrict__ rowptr,
                                                              const int* __restrict__ srcs,
                                                              const __half* __restrict__ hw2h,
                                                              const float* __restrict__ dinv,
                                                              const float* __restrict__ b2,
                                                              float* __restrict__ out) {
    int n = blockIdx.x * 4 + (threadIdx.x >> 6);
    int lane = threadIdx.x & 63;
    int g = lane >> 4;
    int q = lane & 15;
    int s = __builtin_amdgcn_readfirstlane(rowptr[n]);
    int e = __builtin_amdgcn_readfirstlane(rowptr[n + 1]);
    const uint2* vb = (const uint2*)hw2h;
    float4 acc = make_float4(0.f, 0.f, 0.f, 0.f);
    int j = s + g;
    for (; j + 12 < e; j += 16) {
        int i0 = srcs[j], i1 = srcs[j + 4], i2 = srcs[j + 8], i3 = srcs[j + 12];
        uint2 u0 = vb[(size_t)i0 * 16 + q];
        uint2 u1 = vb[(size_t)i1 * 16 + q];
        uint2 u2 = vb[(size_t)i2 * 16 + q];
        uint2 u3 = vb[(size_t)i3 * 16 + q];
        UNPACK_ADD(u0) UNPACK_ADD(u1) UNPACK_ADD(u2) UNPACK_ADD(u3)
    }
    for (; j + 4 < e; j += 8) {
        int i0 = srcs[j], i1 = srcs[j + 4];
        uint2 u0 = vb[(size_t)i0 * 16 + q];
        uint2 u1 = vb[(size_t)i1 * 16 + q];
        UNPACK_ADD(u0) UNPACK_ADD(u1)
    }
    if (j < e) {
        uint2 u0 = vb[(size_t)srcs[j] * 16 + q];
        UNPACK_ADD(u0)
    }
    acc.x += __shfl_xor(acc.x, 16, 64); acc.y += __shfl_xor(acc.y, 16, 64);
    acc.z += __shfl_xor(acc.z, 16, 64); acc.w += __shfl_xor(acc.w, 16, 64);
    acc.x += __shfl_xor(acc.x, 32, 64); acc.y += __shfl_xor(acc.y, 32, 64);
    acc.z += __shfl_xor(acc.z, 32, 64); acc.w += __shfl_xor(acc.w, 32, 64);
    float d = dinv[n];
    uint2 us = vb[(size_t)n * 16 + q];
    __half2 s0 = *reinterpret_cast<__half2*>(&us.x);
    __half2 s1 = *reinterpret_cast<__half2*>(&us.y);
    float2 f0 = __half22float2(s0), f1 = __half22float2(s1);
    const float NEG = -3.402823466e38f;
    float v0 = NEG, v1 = NEG, v2 = NEG, v3 = NEG;
    if (q < 10) {   // quads 0..9 hold the 40 real logits
        float4 bq = *(const float4*)&b2[q * 4];
        v0 = fmaf(d, acc.x + f0.x, bq.x);
        v1 = fmaf(d, acc.y + f0.y, bq.y);
        v2 = fmaf(d, acc.z + f1.x, bq.z);
        v3 = fmaf(d, acc.w + f1.y, bq.w);
    }
    float m = fmaxf(fmaxf(v0, v1), fmaxf(v2, v3));
#pragma unroll
    for (int off = 8; off > 0; off >>= 1) m = fmaxf(m, __shfl_xor(m, off, 64));
    float p0 = 0.f, p1 = 0.f, p2 = 0.f, p3 = 0.f;
    if (q < 10) {
        p0 = __expf(v0 - m); p1 = __expf(v1 - m);
        p2 = __expf(v2 - m); p3 = __expf(v3 - m);
    }
    float su = ((p0 + p1) + (p2 + p3));
#pragma unroll
    for (int off = 8; off > 0; off >>= 1) su += __shfl_xor(su, off, 64);
    if (g == 0 && q < 10) {
        float inv = 1.f / su;
        *(float4*)&out[(size_t)n * F_OUT + q * 4] =
            make_float4(p0 * inv, p1 * inv, p2 * inv, p3 * inv);
    }
}

// ---------------- launch ----------------

extern "C" void kernel_launch(void* const* d_in, const int* in_sizes, int n_in,
                              void* d_out, int out_size, void* d_ws, size_t ws_size,
                              hipStream_t stream) {
    const float* x  = (const float*)d_in[0];
    const int*   ei = (const int*)d_in[1];
    const float* W1 = (const float*)d_in[2];
    const float* b1 = (const float*)d_in[3];
    const float* W2 = (const float*)d_in[4];
    const float* b2 = (const float*)d_in[5];
    float* out = (float*)d_out;

    char* ws = (char*)d_ws;
    size_t off = 0;
    auto alloc = [&](size_t bytes) -> void* {
        void* p = ws + off;
        off += (bytes + 255) & ~(size_t)255;
        return p;
    };
    int*    counts = (int*)   alloc(NC2 * sizeof(int));
    int*    bsum   = (int*)   alloc(NSLICE * sizeof(int));
    int*    choff  = (int*)   alloc(NC2 * sizeof(int));
    int*    pairs  = (int*)   alloc((size_t)N_EDGES * sizeof(int));
    int*    rowptr = (int*)   alloc((N_NODES + 1) * sizeof(int));
    float*  dinv   = (float*) alloc(N_NODES * sizeof(float));
    int*    srcs   = (int*)   alloc((size_t)N_EDGES * sizeof(int));
    __half* hw1h   = (__half*)alloc((size_t)N_NODES * F_MID * sizeof(__half));
    float*  h      = (float*) alloc((size_t)N_NODES * F_MID * sizeof(float));
    __half* hw2h   = (__half*)alloc((size_t)N_NODES * F_MID * sizeof(__half));

    void* args[] = {(void*)&ei, (void*)&counts, (void*)&bsum, (void*)&choff,
                    (void*)&pairs, (void*)&rowptr, (void*)&dinv, (void*)&srcs};
    hipLaunchCooperativeKernel((void*)build_all, dim3(NSLICE), dim3(256), args, 0, stream);

    gemm1_kernel  <<<(N_NODES + 63) / 64, 256, 0, stream>>>(x, W1, dinv, hw1h);
    gather1_kernel<<<N_NODES / 4, 256, 0, stream>>>(rowptr, srcs, hw1h, dinv, b1, h);
    gemm2_kernel  <<<(N_NODES * F_MID) / 256, 256, 0, stream>>>(h, W2, dinv, hw2h);
    gather2_softmax_kernel<<<N_NODES / 4, 256, 0, stream>>>(rowptr, srcs, hw2h, dinv, b2, out);
}

// Round 6
// 212.616 us; speedup vs baseline: 1.5199x; 1.5199x over previous
//
#include <hip/hip_runtime.h>
#include <hip/hip_fp16.h>

#define N_NODES 50000
#define N_EDGES 800000
#define F_IN   128
#define F_MID  64
#define F_OUT  40

// ---- counting-sort CSR build (round-3 proven structure, unchanged) ----
#define SLICE_SHIFT 8
#define SLICE_SZ    256                  // nodes per slice (pow2)
#define NSLICE      196                  // ceil(50000/256)
#define PCHUNKS     256                  // edge chunks for bucket passes
#define PCHUNK_E    ((N_EDGES + PCHUNKS - 1) / PCHUNKS)   // 3125
#define NCOUNT      (NSLICE * PCHUNKS)   // 50176

// ---------------- phase A: per-(chunk,slice) counts, LDS histogram ----------------

__global__ __launch_bounds__(256) void bucket_count(const int* __restrict__ ei,
                                                    int* __restrict__ counts) {
    __shared__ int cnt[NSLICE];
    if (threadIdx.x < NSLICE) cnt[threadIdx.x] = 0;
    __syncthreads();
    int e0 = blockIdx.x * PCHUNK_E;
    int e1 = e0 + PCHUNK_E; if (e1 > N_EDGES) e1 = N_EDGES;
    for (int e = e0 + threadIdx.x; e < e1; e += 256) {
        int c = ei[N_EDGES + e];
        atomicAdd(&cnt[c >> SLICE_SHIFT], 1);
    }
    __syncthreads();
    if (threadIdx.x < NSLICE) counts[threadIdx.x * PCHUNKS + blockIdx.x] = cnt[threadIdx.x];
}

// ---------------- phase B: hierarchical exclusive scan of counts -> choff ----------------

__global__ __launch_bounds__(256) void sc_bsum(const int* __restrict__ counts, int* __restrict__ bsum) {
    int idx = blockIdx.x * 256 + threadIdx.x;
    int v = (idx < NCOUNT) ? counts[idx] : 0;
#pragma unroll
    for (int off = 32; off > 0; off >>= 1) v += __shfl_xor(v, off, 64);
    __shared__ int ws[4];
    if ((threadIdx.x & 63) == 0) ws[threadIdx.x >> 6] = v;
    __syncthreads();
    if (threadIdx.x == 0) bsum[blockIdx.x] = ws[0] + ws[1] + ws[2] + ws[3];
}

__global__ __launch_bounds__(256) void sc_bscan(const int* __restrict__ bsum, int* __restrict__ boff) {
    int tid = threadIdx.x;
    int lane = tid & 63, wv = tid >> 6;
    int v = (tid < NSLICE) ? bsum[tid] : 0;
    int inc = v;
#pragma unroll
    for (int s = 1; s < 64; s <<= 1) {
        int t = __shfl_up(inc, s, 64);
        if (lane >= s) inc += t;
    }
    __shared__ int ws[4];
    if (lane == 63) ws[wv] = inc;
    __syncthreads();
    int woff = 0;
    for (int w = 0; w < wv; ++w) woff += ws[w];
    if (tid < NSLICE) boff[tid] = woff + inc - v;   // exclusive prefix of block sums
}

__global__ __launch_bounds__(256) void sc_bscan2(const int* __restrict__ counts,
                                                 const int* __restrict__ boff,
                                                 int* __restrict__ choff) {
    int idx = blockIdx.x * 256 + threadIdx.x;
    int lane = threadIdx.x & 63, wv = threadIdx.x >> 6;
    int v = (idx < NCOUNT) ? counts[idx] : 0;
    int inc = v;
#pragma unroll
    for (int s = 1; s < 64; s <<= 1) {
        int t = __shfl_up(inc, s, 64);
        if (lane >= s) inc += t;
    }
    __shared__ int ws[4];
    if (lane == 63) ws[wv] = inc;
    __syncthreads();
    int off = boff[blockIdx.x];
    for (int w = 0; w < wv; ++w) off += ws[w];
    if (idx < NCOUNT) choff[idx] = off + inc - v;
}

// ---------------- phase C: scatter packed edges into per-(slice,chunk) ranges ----------------

__global__ __launch_bounds__(256) void bucket_scatter(const int* __restrict__ ei,
                                                      const int* __restrict__ choff,
                                                      int* __restrict__ pairs) {
    __shared__ int cur[NSLICE];
    if (threadIdx.x < NSLICE) cur[threadIdx.x] = choff[threadIdx.x * PCHUNKS + blockIdx.x];
    __syncthreads();
    int e0 = blockIdx.x * PCHUNK_E;
    int e1 = e0 + PCHUNK_E; if (e1 > N_EDGES) e1 = N_EDGES;
    for (int e = e0 + threadIdx.x; e < e1; e += 256) {
        int r = ei[e];
        int c = ei[N_EDGES + e];
        int pos = atomicAdd(&cur[c >> SLICE_SHIFT], 1);
        pairs[pos] = r | ((c & (SLICE_SZ - 1)) << 16);
    }
}

// ---------------- phase D: per-slice CSR build (rowptr, dinv, srcs) ----------------

__global__ __launch_bounds__(256) void slice_csr(const int* __restrict__ pairs,
                                                 const int* __restrict__ choff,
                                                 int* __restrict__ rowptr,
                                                 float* __restrict__ dinv,
                                                 int* __restrict__ srcs) {
    __shared__ int hist[SLICE_SZ];
    __shared__ int wpart[4];
    int s = blockIdx.x;
    int base = choff[s * PCHUNKS];
    int end  = (s == NSLICE - 1) ? N_EDGES : choff[(s + 1) * PCHUNKS];
    int tid = threadIdx.x;
    hist[tid] = 0;
    __syncthreads();
    for (int i = base + tid; i < end; i += 256)
        atomicAdd(&hist[pairs[i] >> 16], 1);
    __syncthreads();
    int v = hist[tid];
    int lane = tid & 63, wv = tid >> 6;
    int inc = v;
#pragma unroll
    for (int st = 1; st < 64; st <<= 1) {
        int t = __shfl_up(inc, st, 64);
        if (lane >= st) inc += t;
    }
    if (lane == 63) wpart[wv] = inc;
    __syncthreads();
    int woff = 0;
    for (int w = 0; w < wv; ++w) woff += wpart[w];
    int ex = woff + inc - v;                 // exclusive prefix within slice
    __syncthreads();
    hist[tid] = ex;                          // reuse hist as cursor (own slot only)
    int node = s * SLICE_SZ + tid;
    if (node < N_NODES) {
        rowptr[node] = base + ex;
        dinv[node]   = rsqrtf((float)v + 1.0f);   // +1 = self loop
    }
    if (node == N_NODES - 1) rowptr[N_NODES] = N_EDGES;
    __syncthreads();
    for (int i = base + tid; i < end; i += 256) {
        int p = pairs[i];
        int pos = atomicAdd(&hist[p >> 16], 1);
        srcs[base + pos] = p & 0xFFFF;
    }
}

// ---------------- GEMM1: hw1h = fp16( (x @ W1) * dinv[row] )  (row = 64 halves = 128 B) ----

__global__ __launch_bounds__(256) void gemm1_kernel(const float* __restrict__ x,
                                                    const float* __restrict__ W1,
                                                    const float* __restrict__ dinv,
                                                    __half* __restrict__ hw1h) {
    __shared__ float sW[F_IN * F_MID];   // 32 KB, row-major [k][c]
    __shared__ float sX[64][68];         // 17 KB, one K-half, padded
    int tid = threadIdx.x;
    const float4* W4 = (const float4*)W1;
    float4* sW4 = (float4*)sW;
    for (int i = tid; i < F_IN * F_MID / 4; i += 256) sW4[i] = W4[i];

    int row0 = blockIdx.x * 64;
    int tx = tid & 15, ty = tid >> 4;
    int c0 = tx * 4, r0 = ty * 4;
    float acc[4][4] = {};

    for (int p = 0; p < 2; ++p) {
        __syncthreads();
#pragma unroll
        for (int it = 0; it < 4; ++it) {
            int i = (tid + it * 256) * 4;
            int r = i >> 6, k = i & 63;
            float4 v = make_float4(0.f, 0.f, 0.f, 0.f);
            if (row0 + r < N_NODES)
                v = *(const float4*)&x[(size_t)(row0 + r) * F_IN + p * 64 + k];
            *(float4*)&sX[r][k] = v;
        }
        __syncthreads();
        const float* sWp = sW + p * 64 * F_MID;
#pragma unroll 4
        for (int k = 0; k < 64; ++k) {
            float4 w = *(const float4*)&sWp[k * F_MID + c0];
            float a0 = sX[r0 + 0][k];
            float a1 = sX[r0 + 1][k];
            float a2 = sX[r0 + 2][k];
            float a3 = sX[r0 + 3][k];
            acc[0][0] = fmaf(a0, w.x, acc[0][0]); acc[0][1] = fmaf(a0, w.y, acc[0][1]);
            acc[0][2] = fmaf(a0, w.z, acc[0][2]); acc[0][3] = fmaf(a0, w.w, acc[0][3]);
            acc[1][0] = fmaf(a1, w.x, acc[1][0]); acc[1][1] = fmaf(a1, w.y, acc[1][1]);
            acc[1][2] = fmaf(a1, w.z, acc[1][2]); acc[1][3] = fmaf(a1, w.w, acc[1][3]);
            acc[2][0] = fmaf(a2, w.x, acc[2][0]); acc[2][1] = fmaf(a2, w.y, acc[2][1]);
            acc[2][2] = fmaf(a2, w.z, acc[2][2]); acc[2][3] = fmaf(a2, w.w, acc[2][3]);
            acc[3][0] = fmaf(a3, w.x, acc[3][0]); acc[3][1] = fmaf(a3, w.y, acc[3][1]);
            acc[3][2] = fmaf(a3, w.z, acc[3][2]); acc[3][3] = fmaf(a3, w.w, acc[3][3]);
        }
    }
#pragma unroll
    for (int j = 0; j < 4; ++j) {
        int row = row0 + r0 + j;
        if (row < N_NODES) {
            float d = dinv[row];
            __half2 p0 = __floats2half2_rn(acc[j][0] * d, acc[j][1] * d);
            __half2 p1 = __floats2half2_rn(acc[j][2] * d, acc[j][3] * d);
            uint2 u = make_uint2(*reinterpret_cast<unsigned int*>(&p0),
                                 *reinterpret_cast<unsigned int*>(&p1));
            *reinterpret_cast<uint2*>(&hw1h[(size_t)row * F_MID + c0]) = u;
        }
    }
}

// ---------------- gather1: h = relu(dinv[n]*(sum_e hw1h[src] + hw1h[n]) + b1) ------------
// Round-3 structure: wave-uniform scalar edge index, lane-per-feature.
// fp16 rows: 64 lanes x 2 B = one 128 B line per edge (was two lines in fp32).

__global__ __launch_bounds__(256) void gather1_kernel(const int* __restrict__ rowptr,
                                                      const int* __restrict__ srcs,
                                                      const __half* __restrict__ hw1h,
                                                      const float* __restrict__ dinv,
                                                      const float* __restrict__ b1,
                                                      float* __restrict__ h) {
    int n = blockIdx.x * 4 + (threadIdx.x >> 6);
    int lane = threadIdx.x & 63;
    if (n >= N_NODES) return;
    int s = __builtin_amdgcn_readfirstlane(rowptr[n]);
    int e = __builtin_amdgcn_readfirstlane(rowptr[n + 1]);
    const __half* hb = hw1h + lane;     // lane-offset base; rows are 64 halves
    float acc = 0.f;
    int j = s;
    for (; j + 8 <= e; j += 8) {
        int i0 = srcs[j + 0], i1 = srcs[j + 1], i2 = srcs[j + 2], i3 = srcs[j + 3];
        int i4 = srcs[j + 4], i5 = srcs[j + 5], i6 = srcs[j + 6], i7 = srcs[j + 7];
        float v0 = __half2float(hb[(size_t)i0 << 6]);
        float v1 = __half2float(hb[(size_t)i1 << 6]);
        float v2 = __half2float(hb[(size_t)i2 << 6]);
        float v3 = __half2float(hb[(size_t)i3 << 6]);
        float v4 = __half2float(hb[(size_t)i4 << 6]);
        float v5 = __half2float(hb[(size_t)i5 << 6]);
        float v6 = __half2float(hb[(size_t)i6 << 6]);
        float v7 = __half2float(hb[(size_t)i7 << 6]);
        acc += ((v0 + v1) + (v2 + v3)) + ((v4 + v5) + (v6 + v7));
    }
    for (; j + 2 <= e; j += 2) {
        int i0 = srcs[j], i1 = srcs[j + 1];
        acc += __half2float(hb[(size_t)i0 << 6]) + __half2float(hb[(size_t)i1 << 6]);
    }
    if (j < e) acc += __half2float(hb[(size_t)srcs[j] << 6]);
    float d = dinv[n];
    float v = fmaf(d, acc + __half2float(hb[(size_t)n << 6]), b1[lane]);
    h[(size_t)n * F_MID + lane] = fmaxf(v, 0.f);
}

// ---------------- GEMM2: hw2h = fp16( (h @ W2) * dinv[row] ), rows padded 40 -> 64 halves ----

__global__ __launch_bounds__(256) void gemm2_kernel(const float* __restrict__ h,
                                                    const float* __restrict__ W2,
                                                    const float* __restrict__ dinv,
                                                    __half* __restrict__ hw2h) {
    __shared__ float sW[F_MID * F_OUT];  // 10 KB
    for (int i = threadIdx.x; i < F_MID * F_OUT; i += 256) sW[i] = W2[i];
    __syncthreads();
    int idx = blockIdx.x * 256 + threadIdx.x;      // over N_NODES * 64 (padded rows)
    int r = idx >> 6;
    int c = idx & 63;
    float acc = 0.f;
    if (c < F_OUT) {
        const float* hr = h + (size_t)r * F_MID;
#pragma unroll
        for (int k = 0; k < F_MID; ++k) acc = fmaf(hr[k], sW[k * F_OUT + c], acc);
        acc *= dinv[r];
    }
    hw2h[idx] = __float2half(acc);                 // cols 40..63 = 0 (inert in gather)
}

// ---------------- gather2 + softmax (fp16 padded rows: one 128 B line per edge) -----------

__global__ __launch_bounds__(256) void gather2_softmax_kernel(const int* __restrict__ rowptr,
                                                              const int* __restrict__ srcs,
                                                              const __half* __restrict__ hw2h,
                                                              const float* __restrict__ dinv,
                                                              const float* __restrict__ b2,
                                                              float* __restrict__ out) {
    int n = blockIdx.x * 4 + (threadIdx.x >> 6);
    int lane = threadIdx.x & 63;
    if (n >= N_NODES) return;
    int s = __builtin_amdgcn_readfirstlane(rowptr[n]);
    int e = __builtin_amdgcn_readfirstlane(rowptr[n + 1]);
    const __half* gb = hw2h + lane;                // rows are 64 halves (pad reads 0)
    float acc = 0.f;
    int j = s;
    for (; j + 8 <= e; j += 8) {
        int i0 = srcs[j + 0], i1 = srcs[j + 1], i2 = srcs[j + 2], i3 = srcs[j + 3];
        int i4 = srcs[j + 4], i5 = srcs[j + 5], i6 = srcs[j + 6], i7 = srcs[j + 7];
        float v0 = __half2float(gb[(size_t)i0 << 6]);
        float v1 = __half2float(gb[(size_t)i1 << 6]);
        float v2 = __half2float(gb[(size_t)i2 << 6]);
        float v3 = __half2float(gb[(size_t)i3 << 6]);
        float v4 = __half2float(gb[(size_t)i4 << 6]);
        float v5 = __half2float(gb[(size_t)i5 << 6]);
        float v6 = __half2float(gb[(size_t)i6 << 6]);
        float v7 = __half2float(gb[(size_t)i7 << 6]);
        acc += ((v0 + v1) + (v2 + v3)) + ((v4 + v5) + (v6 + v7));
    }
    for (; j + 2 <= e; j += 2) {
        int i0 = srcs[j], i1 = srcs[j + 1];
        acc += __half2float(gb[(size_t)i0 << 6]) + __half2float(gb[(size_t)i1 << 6]);
    }
    if (j < e) acc += __half2float(gb[(size_t)srcs[j] << 6]);
    float d = dinv[n];
    float v = -3.402823466e38f;
    if (lane < F_OUT)
        v = fmaf(d, acc + __half2float(gb[(size_t)n << 6]), b2[lane]);
    float m = v;
#pragma unroll
    for (int off = 32; off > 0; off >>= 1) m = fmaxf(m, __shfl_xor(m, off, 64));
    float p = (lane < F_OUT) ? __expf(v - m) : 0.f;
    float su = p;
#pragma unroll
    for (int off = 32; off > 0; off >>= 1) su += __shfl_xor(su, off, 64);
    if (lane < F_OUT) out[(size_t)n * F_OUT + lane] = p / su;
}

// ---------------- launch ----------------

extern "C" void kernel_launch(void* const* d_in, const int* in_sizes, int n_in,
                              void* d_out, int out_size, void* d_ws, size_t ws_size,
                              hipStream_t stream) {
    const float* x  = (const float*)d_in[0];
    const int*   ei = (const int*)d_in[1];
    const float* W1 = (const float*)d_in[2];
    const float* b1 = (const float*)d_in[3];
    const float* W2 = (const float*)d_in[4];
    const float* b2 = (const float*)d_in[5];
    float* out = (float*)d_out;

    char* ws = (char*)d_ws;
    size_t off = 0;
    auto alloc = [&](size_t bytes) -> void* {
        void* p = ws + off;
        off += (bytes + 255) & ~(size_t)255;
        return p;
    };
    int*    counts = (int*)   alloc(NCOUNT * sizeof(int));
    int*    bsum   = (int*)   alloc(NSLICE * sizeof(int));
    int*    boff   = (int*)   alloc(NSLICE * sizeof(int));
    int*    choff  = (int*)   alloc(NCOUNT * sizeof(int));
    int*    pairs  = (int*)   alloc((size_t)N_EDGES * sizeof(int));
    int*    rowptr = (int*)   alloc((N_NODES + 1) * sizeof(int));
    float*  dinv   = (float*) alloc(N_NODES * sizeof(float));
    int*    srcs   = (int*)   alloc((size_t)N_EDGES * sizeof(int));
    __half* hw1h   = (__half*)alloc((size_t)N_NODES * F_MID * sizeof(__half));
    float*  h      = (float*) alloc((size_t)N_NODES * F_MID * sizeof(float));
    __half* hw2h   = (__half*)alloc((size_t)N_NODES * F_MID * sizeof(__half));

    bucket_count  <<<PCHUNKS, 256, 0, stream>>>(ei, counts);
    sc_bsum       <<<(NCOUNT + 255) / 256, 256, 0, stream>>>(counts, bsum);
    sc_bscan      <<<1, 256, 0, stream>>>(bsum, boff);
    sc_bscan2     <<<(NCOUNT + 255) / 256, 256, 0, stream>>>(counts, boff, choff);
    bucket_scatter<<<PCHUNKS, 256, 0, stream>>>(ei, choff, pairs);
    slice_csr     <<<NSLICE, 256, 0, stream>>>(pairs, choff, rowptr, dinv, srcs);
    gemm1_kernel  <<<(N_NODES + 63) / 64, 256, 0, stream>>>(x, W1, dinv, hw1h);
    gather1_kernel<<<(N_NODES + 3) / 4, 256, 0, stream>>>(rowptr, srcs, hw1h, dinv, b1, h);
    gemm2_kernel  <<<(N_NODES * F_MID) / 256, 256, 0, stream>>>(h, W2, dinv, hw2h);
    gather2_softmax_kernel<<<(N_NODES + 3) / 4, 256, 0, stream>>>(rowptr, srcs, hw2h, dinv, b2, out);
}